// Round 17
// baseline (151.496 us; speedup 1.0000x reference)
//
#include <hip/hip_runtime.h>

// ---------------------------------------------------------------------------
// GalerkinAttention on MI355X (gfx950), round 17 = r15 champion (126.0us)
// with k1 re-tiled for CO-RESIDENCY: 64-row tiles, 2-wave (128-thread)
// blocks, grid 4096, LDS 24KB -> 6 blocks/CU (vs measured ~2.3 at r15).
// Per-wave work profile identical to champion (same loads/cvt/MFMA/ledger);
// only the barrier width (2 waves) and block count change. r16 lesson:
// B-latency prefetch is neutral -> keep champion's same-iter B staging.
//
// Shapes: B=4, N=8192, D=512, H=8, Dh=64. Algebra: y = x @ M_b^T + b_out,
//   M_b[d'][d] = sum_h W_out[d',h-blk] . P_bh . W_q[h-blk,d] / n
//
// k1 block: 64 rows x head h. Wave w (of 2): stages A rows w*32..+31
// (f32->cvt->ds_write) and B rows of ITS OWN k|v group (w=0 k, w=1 v;
// 64 rows, 8 gload_lds); computes all 64 n-rows x its 64 cols (4x4 frags).
// vmcnt ledger/iter: cvt A(t) implicit-drains all; issue B(t):8, A(t+1):8
// -> vmcnt(8) drains B(t), keeps A(t+1) in flight. Tail: vmcnt(0).
// Epilogue: LN per wave group -> kn->As, vn->Bs[0..4095] ([64d][64n],
// 8-group XOR transpose) -> P-partial (wave w: dh rows w*32..+31, 16 MFMA)
// -> bf16 stores to Ppart[bh][slab=rt&127].
//
// MFMA 16x16x32 bf16 (verified r1-16):
//   A frag: lane l holds A[row=l&15][k = ks*32 + (l>>4)*8 + e]
//   B frag: lane l holds B[col=l&15][same k]
//   C/D   : lane l reg r -> C[row=(l>>4)*4+r][col=l&15]
// LDS swizzle (8-short XOR, PMC-verified 0 conflicts):
//   stage src col pre-swizzled ((l&7)^(l>>3))*8; read col ^ ((c16&7)<<3)
// Epilogue kn/vn LDS ([64 d][64 n], 8-short-granular XOR):
//   phys_short(d,n) = d*64 + (((n>>3) ^ (d&7))<<3) + (n&7)
// ---------------------------------------------------------------------------

typedef __attribute__((ext_vector_type(8))) short bf16x8;
typedef __attribute__((ext_vector_type(4))) float f32x4;
typedef __attribute__((ext_vector_type(4))) unsigned short u16x4;
typedef __attribute__((ext_vector_type(4))) unsigned int u32x4;

__device__ __forceinline__ unsigned short f2bf(float f) {
  unsigned int u = __builtin_bit_cast(unsigned int, f);
  u += 0x7FFFu + ((u >> 16) & 1u);   // RNE
  return (unsigned short)(u >> 16);
}

__device__ __forceinline__ float bf2f(unsigned short h) {
  unsigned int u = ((unsigned int)h) << 16;
  return __builtin_bit_cast(float, u);
}

__device__ __forceinline__ unsigned int cvt2(float lo, float hi) {
  return ((unsigned int)f2bf(hi) << 16) | (unsigned int)f2bf(lo);
}

__device__ __forceinline__ f32x4 mfma16(bf16x8 a, bf16x8 b, f32x4 c) {
  return __builtin_amdgcn_mfma_f32_16x16x32_bf16(a, b, c, 0, 0, 0);
}

__device__ __forceinline__ void gload16(const void* g, void* l) {
  __builtin_amdgcn_global_load_lds(
      (const __attribute__((address_space(1))) void*)g,
      (__attribute__((address_space(3))) void*)l, 16, 0, 0);
}

// ------------------------ K0: convert weights (merged) ----------------------
__global__ void k_cvt_w(const float* __restrict__ Wqkv,
                        const float* __restrict__ Wout,
                        unsigned short* __restrict__ Wb,
                        unsigned short* __restrict__ Wob) {
  int i = blockIdx.x * 256 + threadIdx.x;
  const float4* src;
  u16x4* dst;
  if (i < 196608) { src = (const float4*)Wqkv + i; dst = (u16x4*)Wb + i; }
  else { i -= 196608; src = (const float4*)Wout + i; dst = (u16x4*)Wob + i; }
  float4 v = *src;
  u16x4 o;
  o[0] = f2bf(v.x); o[1] = f2bf(v.y); o[2] = f2bf(v.z); o[3] = f2bf(v.w);
  *dst = o;
}

// ------------ K1: 64-row 2-wave kv GEMM + LN + P (6 blocks/CU) --------------
// 1D grid 4096 (XCD-swizzled): wgid=(bid&7)*512+(bid>>3); rt=wgid>>3, h=wgid&7
__launch_bounds__(128, 4)
__global__ void k1_kvp(const float* __restrict__ x,
                       const unsigned short* __restrict__ wqkvb,
                       const float* __restrict__ gK, const float* __restrict__ bK,
                       const float* __restrict__ gV, const float* __restrict__ bV,
                       unsigned short* __restrict__ Ppart) {
  __shared__ __align__(16) unsigned short As[4096];   //  8 KB: A [64][64]
  __shared__ __align__(16) unsigned short Bs[8192];   // 16 KB: B [128][64]
  const int bid = (int)blockIdx.x;
  const int wgid = (bid & 7) * 512 + (bid >> 3);      // bijective (4096%8==0)
  const int rt = wgid >> 3, h = wgid & 7;
  const int tid = (int)threadIdx.x;
  const int l = tid & 63, w = tid >> 6;               // w in {0,1}: 0=k, 1=v
  const int g = l >> 4, c16 = l & 15;
  const int row0 = rt * 64;
  const int swz = ((l & 7) ^ (l >> 3)) * 8;           // logical col in 64-blk

  const float* gx = x + (size_t)(row0 + w * 32 + (l >> 3)) * 512 + swz;
  const int bbase = (w == 0) ? 512 : 1024;            // k rows | v rows
  const unsigned short* gsB = wqkvb + (bbase + h * 64 + (l >> 3)) * 512 + swz;
  unsigned short* la = As + w * 2048 + l * 8;         // + j*512 per row-slice

  f32x4 acc[4][4] = {};
  float4 pf[8];

  // prologue: A(0) f32 loads
#pragma unroll
  for (int j = 0; j < 4; ++j) {
    pf[2 * j]     = *(const float4*)(gx + j * 4096);
    pf[2 * j + 1] = *(const float4*)(gx + j * 4096 + 4);
  }

  for (int kt = 0; kt < 8; ++kt) {
    // convert + write A(kt); compiler's implicit wait drains the pf loads
#pragma unroll
    for (int j = 0; j < 4; ++j) {
      u32x4 c;
      c[0] = cvt2(pf[2 * j].x, pf[2 * j].y);
      c[1] = cvt2(pf[2 * j].z, pf[2 * j].w);
      c[2] = cvt2(pf[2 * j + 1].x, pf[2 * j + 1].y);
      c[3] = cvt2(pf[2 * j + 1].z, pf[2 * j + 1].w);
      *(u32x4*)(la + j * 512) = c;
    }
    // stage B(kt): wave's own 64 rows (8 x gload_lds)
#pragma unroll
    for (int j = 0; j < 8; ++j)
      gload16(gsB + kt * 64 + j * 8 * 512, Bs + w * 4096 + j * 512);
    __builtin_amdgcn_sched_barrier(0);   // pin: B gloads BEFORE A prefetch
    if (kt < 7) {
#pragma unroll
      for (int j = 0; j < 4; ++j) {
        pf[2 * j]     = *(const float4*)(gx + (kt + 1) * 64 + j * 4096);
        pf[2 * j + 1] = *(const float4*)(gx + (kt + 1) * 64 + j * 4096 + 4);
      }
      asm volatile("s_waitcnt vmcnt(8) lgkmcnt(0)" ::: "memory");
    } else {
      asm volatile("s_waitcnt vmcnt(0) lgkmcnt(0)" ::: "memory");
    }
    __builtin_amdgcn_sched_barrier(0);
    __builtin_amdgcn_s_barrier();        // tile ready (2-wave barrier)
    // compute: all 64 A rows x wave's own 64 B cols
#pragma unroll
    for (int ks = 0; ks < 2; ++ks) {
      const int kcol = (ks * 32 + g * 8) ^ ((c16 & 7) << 3);
      bf16x8 af[4], bfv[4];
#pragma unroll
      for (int mi = 0; mi < 4; ++mi)
        af[mi] = *(const bf16x8*)&As[(mi * 16 + c16) * 64 + kcol];
#pragma unroll
      for (int ni = 0; ni < 4; ++ni)
        bfv[ni] = *(const bf16x8*)&Bs[w * 4096 + (ni * 16 + c16) * 64 + kcol];
#pragma unroll
      for (int mi = 0; mi < 4; ++mi)
#pragma unroll
        for (int ni = 0; ni < 4; ++ni)
          acc[mi][ni] = mfma16(af[mi], bfv[ni], acc[mi][ni]);
    }
    __builtin_amdgcn_sched_barrier(0);
    __builtin_amdgcn_s_barrier();        // LDS free for next kt's writes
  }

  // ---- per-head LayerNorm (wave group: w=0 -> k, w=1 -> v)
  const float* gamma = (w == 0) ? gK : gV;
  const float* beta  = (w == 0) ? bK : bV;
  float gm[4], bt[4];
#pragma unroll
  for (int ni = 0; ni < 4; ++ni) {
    gm[ni] = gamma[h * 64 + ni * 16 + c16];
    bt[ni] = beta[h * 64 + ni * 16 + c16];
  }
  // kn -> As ([64 d][64 n]), vn -> Bs[0..4095]
  unsigned short* dst = (w == 0) ? As : Bs;
#pragma unroll
  for (int mi = 0; mi < 4; ++mi) {
    float mean4[4], rs4[4];
#pragma unroll
    for (int r = 0; r < 4; ++r) {
      float a0 = acc[mi][0][r], a1 = acc[mi][1][r];
      float a2 = acc[mi][2][r], a3 = acc[mi][3][r];
      float s1 = a0 + a1 + a2 + a3;
      float s2 = a0 * a0 + a1 * a1 + a2 * a2 + a3 * a3;
#pragma unroll
      for (int m = 1; m <= 8; m <<= 1) {   // reduce over 16-lane col group
        s1 += __shfl_xor(s1, m, 64);
        s2 += __shfl_xor(s2, m, 64);
      }
      const float mean = s1 * (1.0f / 64.0f);
      const float var = s2 * (1.0f / 64.0f) - mean * mean;
      mean4[r] = mean;
      rs4[r] = rsqrtf(var + 1e-5f);
    }
    const int n0 = mi * 16 + g * 4;
#pragma unroll
    for (int ni = 0; ni < 4; ++ni) {
      u16x4 o;
#pragma unroll
      for (int r = 0; r < 4; ++r)
        o[r] = f2bf((acc[mi][ni][r] - mean4[r]) * rs4[r] * gm[ni] + bt[ni]);
      // phys8 = (n>>3) ^ (d&7); d&7 == c16&7
      *(u16x4*)&dst[(ni * 16 + c16) * 64 + (((n0 >> 3) ^ (c16 & 7)) << 3) + (n0 & 7)] = o;
    }
  }
  __syncthreads();

  // ---- P-partial: wave w covers dh rows w*32..w*32+31, all 64 dv, n=64
  const unsigned short* Kl = As;
  const unsigned short* Vl = Bs;
  f32x4 pacc[2][4] = {};
#pragma unroll
  for (int ks = 0; ks < 2; ++ks) {
    const int grp = (((ks * 4 + g) ^ (c16 & 7)) << 3);
    bf16x8 af[2], bv[4];
#pragma unroll
    for (int m2 = 0; m2 < 2; ++m2)
      af[m2] = *(const bf16x8*)&Kl[(w * 32 + m2 * 16 + c16) * 64 + grp];
#pragma unroll
    for (int ni = 0; ni < 4; ++ni)
      bv[ni] = *(const bf16x8*)&Vl[(ni * 16 + c16) * 64 + grp];
#pragma unroll
    for (int m2 = 0; m2 < 2; ++m2)
#pragma unroll
      for (int ni = 0; ni < 4; ++ni)
        pacc[m2][ni] = mfma16(af[m2], bv[ni], pacc[m2][ni]);
  }
  // bf16 partial stores: Ppart[bh][slab][dh][dv], slab = rt & 127
  const int bh = (rt >> 7) * 8 + h;
  unsigned short* Pp = Ppart + ((size_t)(bh * 128 + (rt & 127))) * 4096;
#pragma unroll
  for (int m2 = 0; m2 < 2; ++m2)
#pragma unroll
    for (int ni = 0; ni < 4; ++ni)
#pragma unroll
      for (int r = 0; r < 4; ++r)
        Pp[(w * 32 + m2 * 16 + g * 4 + r) * 64 + ni * 16 + c16] =
            f2bf(pacc[m2][ni][r]);
}

// ---------------- KR: P[bh] = sum over 128 slabs of Ppart (bf16) ------------
__launch_bounds__(256)
__global__ void k_preduce(const unsigned short* __restrict__ Ppart,
                          float* __restrict__ P) {
  const int bh = blockIdx.x;
  const int e = blockIdx.y * 256 + threadIdx.x;
  const unsigned short* src = Ppart + (size_t)bh * 128 * 4096 + e;
  float s = 0.f;
#pragma unroll 8
  for (int sl = 0; sl < 128; ++sl) s += bf2f(src[sl * 4096]);
  P[bh * 4096 + e] = s;
}

// ------------- K3a: Gt[b][d][h*64+dv] = sum_dh P[bh][dh][dv]*Wq[h*64+dh][d]/n
__launch_bounds__(256)
__global__ void k3a_g(const float* __restrict__ Wqkv,
                      const float* __restrict__ P,
                      unsigned short* __restrict__ Gt) {
  __shared__ float Pl[64 * 64];
  const int bh = blockIdx.x, dd = blockIdx.y;
  const int b = bh >> 3, h = bh & 7;
  const int t = (int)threadIdx.x;
  for (int i = t; i < 1024; i += 256)
    ((float4*)Pl)[i] = ((const float4*)(P + bh * 4096))[i];
  __syncthreads();

  const int qg = t >> 6, dl = t & 63;
  const int d = dd * 64 + dl;
  float acc[16] = {};
  for (int dh = 0; dh < 64; ++dh) {
    const float wq = Wqkv[(h * 64 + dh) * 512 + d];
    const float* pr = &Pl[dh * 64 + qg * 16];
#pragma unroll
    for (int i = 0; i < 16; ++i) acc[i] += pr[i] * wq;
  }
  unsigned short* go = &Gt[(b * 512 + d) * 512 + h * 64 + qg * 16];
#pragma unroll
  for (int i = 0; i < 16; ++i) go[i] = f2bf(acc[i] * (1.0f / 8192.0f));
}

// ----------------------- 128^2 single-buffer GEMM pieces --------------------
__device__ __forceinline__ void stage_tile(const unsigned short* pa,
                                           const unsigned short* pb,
                                           unsigned short* As, unsigned short* Bs,
                                           int w) {
#pragma unroll
  for (int j = 0; j < 4; ++j) {
    gload16(pa + j * 8 * 512, As + w * 2048 + j * 512);
    gload16(pb + j * 8 * 512, Bs + w * 2048 + j * 512);
  }
}

__device__ __forceinline__ void compute_tile(const unsigned short* As,
                                             const unsigned short* Bs,
                                             int wr, int wc, int g, int c16,
                                             f32x4 acc[4][4]) {
#pragma unroll
  for (int ks = 0; ks < 2; ++ks) {
    const int kcol = (ks * 32 + g * 8) ^ ((c16 & 7) << 3);
    bf16x8 af[4], bfv[4];
#pragma unroll
    for (int mi = 0; mi < 4; ++mi)
      af[mi] = *(const bf16x8*)&As[(wr * 64 + mi * 16 + c16) * 64 + kcol];
#pragma unroll
    for (int ni = 0; ni < 4; ++ni)
      bfv[ni] = *(const bf16x8*)&Bs[(wc * 64 + ni * 16 + c16) * 64 + kcol];
#pragma unroll
    for (int mi = 0; mi < 4; ++mi)
#pragma unroll
      for (int ni = 0; ni < 4; ++ni)
        acc[mi][ni] = mfma16(af[mi], bfv[ni], acc[mi][ni]);
  }
}

// ----------- K3b: M_b[d'][d] = sum_e Wout[d'][e] * Gt_b[d][e] ---------------
__launch_bounds__(256)
__global__ void k3b_m(const unsigned short* __restrict__ wob,
                      const unsigned short* __restrict__ Gt,
                      unsigned short* __restrict__ Mb) {
  __shared__ __align__(16) unsigned short As[8192];
  __shared__ __align__(16) unsigned short Bs[8192];
  const int rt = blockIdx.x, ct = blockIdx.y, b = blockIdx.z;
  const int tid = (int)threadIdx.x;
  const int l = tid & 63, w = tid >> 6;
  const int wr = w >> 1, wc = w & 1;
  const int g = l >> 4, c16 = l & 15;
  const int row0 = rt * 128, col0 = ct * 128;
  const int swz = ((l & 7) ^ (l >> 3)) * 8;

  const unsigned short* gsA = wob + (row0 + w * 32 + (l >> 3)) * 512 + swz;
  const unsigned short* gsB = Gt + b * 262144 + (col0 + w * 32 + (l >> 3)) * 512 + swz;

  f32x4 acc[4][4] = {};
  for (int kt = 0; kt < 8; ++kt) {
    stage_tile(gsA + kt * 64, gsB + kt * 64, As, Bs, w);
    __syncthreads();
    compute_tile(As, Bs, wr, wc, g, c16, acc);
    __syncthreads();
  }

#pragma unroll
  for (int mi = 0; mi < 4; ++mi)
#pragma unroll
    for (int ni = 0; ni < 4; ++ni) {
      const int colg = col0 + wc * 64 + ni * 16 + c16;
#pragma unroll
      for (int r = 0; r < 4; ++r) {
        const int rowg = row0 + wr * 64 + mi * 16 + g * 4 + r;
        Mb[(b * 512 + rowg) * 512 + colg] = f2bf(acc[mi][ni][r]);
      }
    }
}

// ---------------- K4: y = x @ M_b^T + b_out (A reg-staged f32) --------------
// 1D grid 1024 (XCD-swizzled): wgid=(bid&7)*128+(bid>>3); rt=wgid>>2, ct=wgid&3
__launch_bounds__(256, 3)
__global__ void k4_final(const float* __restrict__ x,
                         const unsigned short* __restrict__ Mb,
                         const float* __restrict__ bout,
                         float* __restrict__ y) {
  __shared__ __align__(16) unsigned short As[8192];
  __shared__ __align__(16) unsigned short Bs[8192];
  const int bid = (int)blockIdx.x;
  const int wgid = (bid & 7) * 128 + (bid >> 3);      // bijective (1024%8==0)
  const int rt = wgid >> 2, ct = wgid & 3;
  const int tid = (int)threadIdx.x;
  const int l = tid & 63, w = tid >> 6;
  const int wr = w >> 1, wc = w & 1;
  const int g = l >> 4, c16 = l & 15;
  const int row0 = rt * 128, col0 = ct * 128;
  const int bb = row0 >> 13;
  const int swz = ((l & 7) ^ (l >> 3)) * 8;

  const float* gx = x + (size_t)(row0 + w * 32 + (l >> 3)) * 512 + swz;
  const unsigned short* gsB =
      Mb + (size_t)bb * 262144 + (col0 + w * 32 + (l >> 3)) * 512 + swz;
  unsigned short* la = As + w * 2048 + l * 8;

  f32x4 acc[4][4] = {};
  float4 pf[8];
#pragma unroll
  for (int j = 0; j < 4; ++j) {
    pf[2 * j]     = *(const float4*)(gx + j * 4096);
    pf[2 * j + 1] = *(const float4*)(gx + j * 4096 + 4);
  }

  for (int kt = 0; kt < 8; ++kt) {
#pragma unroll
    for (int j = 0; j < 4; ++j) {
      u32x4 c;
      c[0] = cvt2(pf[2 * j].x, pf[2 * j].y);
      c[1] = cvt2(pf[2 * j].z, pf[2 * j].w);
      c[2] = cvt2(pf[2 * j + 1].x, pf[2 * j + 1].y);
      c[3] = cvt2(pf[2 * j + 1].z, pf[2 * j + 1].w);
      *(u32x4*)(la + j * 512) = c;
    }
#pragma unroll
    for (int j = 0; j < 4; ++j)
      gload16(gsB + kt * 64 + j * 8 * 512, Bs + w * 2048 + j * 512);
    __builtin_amdgcn_sched_barrier(0);
    if (kt < 7) {
#pragma unroll
      for (int j = 0; j < 4; ++j) {
        pf[2 * j]     = *(const float4*)(gx + (kt + 1) * 64 + j * 4096);
        pf[2 * j + 1] = *(const float4*)(gx + (kt + 1) * 64 + j * 4096 + 4);
      }
      asm volatile("s_waitcnt vmcnt(8) lgkmcnt(0)" ::: "memory");
    } else {
      asm volatile("s_waitcnt vmcnt(0) lgkmcnt(0)" ::: "memory");
    }
    __builtin_amdgcn_sched_barrier(0);
    __builtin_amdgcn_s_barrier();
#pragma unroll
    for (int ks = 0; ks < 2; ++ks) {
      const int kcol = (ks * 32 + g * 8) ^ ((c16 & 7) << 3);
      bf16x8 af[4], bfv[4];
#pragma unroll
      for (int mi = 0; mi < 4; ++mi)
        af[mi] = *(const bf16x8*)&As[(wr * 64 + mi * 16 + c16) * 64 + kcol];
#pragma unroll
      for (int ni = 0; ni < 4; ++ni)
        bfv[ni] = *(const bf16x8*)&Bs[(wc * 64 + ni * 16 + c16) * 64 + kcol];
#pragma unroll
      for (int mi = 0; mi < 4; ++mi)
#pragma unroll
        for (int ni = 0; ni < 4; ++ni)
          acc[mi][ni] = mfma16(af[mi], bfv[ni], acc[mi][ni]);
    }
    __builtin_amdgcn_sched_barrier(0);
    __builtin_amdgcn_s_barrier();
  }

  float bo[4];
#pragma unroll
  for (int ni = 0; ni < 4; ++ni)
    bo[ni] = bout[col0 + wc * 64 + ni * 16 + c16];
#pragma unroll
  for (int mi = 0; mi < 4; ++mi)
#pragma unroll
    for (int ni = 0; ni < 4; ++ni) {
      const int colg = col0 + wc * 64 + ni * 16 + c16;
#pragma unroll
      for (int r = 0; r < 4; ++r) {
        const int rowg = row0 + wr * 64 + mi * 16 + g * 4 + r;
        y[rowg * 512 + colg] = acc[mi][ni][r] + bo[ni];
      }
    }
}

// ---------------------------------------------------------------------------
extern "C" void kernel_launch(void* const* d_in, const int* in_sizes, int n_in,
                              void* d_out, int out_size, void* d_ws, size_t ws_size,
                              hipStream_t stream) {
  (void)in_sizes; (void)n_in; (void)out_size; (void)ws_size;
  const float* x    = (const float*)d_in[0];
  const float* Wqkv = (const float*)d_in[1];
  const float* gK   = (const float*)d_in[2];
  const float* bK   = (const float*)d_in[3];
  const float* gV   = (const float*)d_in[4];
  const float* bV   = (const float*)d_in[5];
  const float* Wout = (const float*)d_in[6];
  const float* bout = (const float*)d_in[7];
  float* y = (float*)d_out;

  // workspace carve (~40 MB)
  char* w = (char*)d_ws;
  unsigned short* Wb    = (unsigned short*)(w);             //  1,572,864
  unsigned short* Wob   = (unsigned short*)(w + 1572864);   //    524,288
  float*          P     = (float*)         (w + 2097152);   //    524,288
  unsigned short* Gt    = (unsigned short*)(w + 2621440);   //  2,097,152
  unsigned short* Mb    = (unsigned short*)(w + 4718592);   //  2,097,152
  unsigned short* Ppart = (unsigned short*)(w + 6815744);   // 33,554,432

  k_cvt_w<<<1024, 256, 0, stream>>>(Wqkv, Wout, Wb, Wob);

  k1_kvp<<<4096, 128, 0, stream>>>(x, Wb, gK, bK, gV, bV, Ppart);
  k_preduce<<<dim3(32, 16), 256, 0, stream>>>(Ppart, P);
  k3a_g<<<dim3(32, 8), 256, 0, stream>>>(Wqkv, P, Gt);
  k3b_m<<<dim3(4, 4, 4), 256, 0, stream>>>(Wob, Gt, Mb);
  k4_final<<<1024, 256, 0, stream>>>(x, Mb, bout, y);
}

// Round 18
// 125.312 us; speedup vs baseline: 1.2089x; 1.2089x over previous
//
#include <hip/hip_runtime.h>

// ---------------------------------------------------------------------------
// GalerkinAttention on MI355X (gfx950), round 18 = r15 CHAMPION RESTORED
// (126.0us, absmax 4.8e-7). r17's co-residency retile regressed (151.5us,
// VGPR 112, occupancy 19%) and is reverted.
//
// Final structure:
//   K0 : convert W_qkv, W_out to bf16 (merged)
//   K1 : per (128-row-tile, head): kv = x @ W^T; A reg-staged from f32
//        (1-deep prefetch, cvt fused), B via global_load_lds; 32KB LDS,
//        2 barriers/kt; epilogue: in-register LN -> kn/vn to LDS (16B-XOR
//        transpose) -> P-partial MFMA -> bf16 stores to Ppart (no atomics)
//   KR : P[bh] = sum_slab Ppart (512 blocks, f32 accum)
//   K3a: Gt[b][d][h*64+dv] = sum_dh P[bh][dh][dv] * Wqkv[h*64+dh][d]/8192
//   K3b: M_b = Wout_bf16 @ Gt_b (single-buffer 128^2 GEMM)
//   K4 : y = x @ M_b^T + b_out (A reg-staged f32, B gload_lds, fp32 store)
//
// MFMA 16x16x32 bf16 (verified r1-17):
//   A frag: lane l holds A[row=l&15][k = ks*32 + (l>>4)*8 + e]
//   B frag: lane l holds B[col=l&15][same k]
//   C/D   : lane l reg r -> C[row=(l>>4)*4+r][col=l&15]
// LDS swizzle (8-short XOR, PMC-verified 0 conflicts):
//   stage src col pre-swizzled ((l&7)^(l>>3))*8; read col ^ ((c16&7)<<3)
// Epilogue kn/vn LDS ([64 d][128 n], 16B-granular XOR):
//   phys_short(d,n) = d*128 + ((n>>3)^(d&15))*8 + (n&7)
// k1/k4 vmcnt ledger: [4x gload_lds B] then [8x dwordx4 A(kt+1)] (order
//   pinned by sched_barrier(0)) -> vmcnt(8) drains B, keeps A in flight.
// ---------------------------------------------------------------------------

typedef __attribute__((ext_vector_type(8))) short bf16x8;
typedef __attribute__((ext_vector_type(4))) float f32x4;
typedef __attribute__((ext_vector_type(4))) unsigned short u16x4;
typedef __attribute__((ext_vector_type(4))) unsigned int u32x4;

__device__ __forceinline__ unsigned short f2bf(float f) {
  unsigned int u = __builtin_bit_cast(unsigned int, f);
  u += 0x7FFFu + ((u >> 16) & 1u);   // RNE
  return (unsigned short)(u >> 16);
}

__device__ __forceinline__ float bf2f(unsigned short h) {
  unsigned int u = ((unsigned int)h) << 16;
  return __builtin_bit_cast(float, u);
}

__device__ __forceinline__ unsigned int cvt2(float lo, float hi) {
  return ((unsigned int)f2bf(hi) << 16) | (unsigned int)f2bf(lo);
}

__device__ __forceinline__ f32x4 mfma16(bf16x8 a, bf16x8 b, f32x4 c) {
  return __builtin_amdgcn_mfma_f32_16x16x32_bf16(a, b, c, 0, 0, 0);
}

__device__ __forceinline__ void gload16(const void* g, void* l) {
  __builtin_amdgcn_global_load_lds(
      (const __attribute__((address_space(1))) void*)g,
      (__attribute__((address_space(3))) void*)l, 16, 0, 0);
}

// ------------------------ K0: convert weights (merged) ----------------------
__global__ void k_cvt_w(const float* __restrict__ Wqkv,
                        const float* __restrict__ Wout,
                        unsigned short* __restrict__ Wb,
                        unsigned short* __restrict__ Wob) {
  int i = blockIdx.x * 256 + threadIdx.x;
  const float4* src;
  u16x4* dst;
  if (i < 196608) { src = (const float4*)Wqkv + i; dst = (u16x4*)Wb + i; }
  else { i -= 196608; src = (const float4*)Wout + i; dst = (u16x4*)Wob + i; }
  float4 v = *src;
  u16x4 o;
  o[0] = f2bf(v.x); o[1] = f2bf(v.y); o[2] = f2bf(v.z); o[3] = f2bf(v.w);
  *dst = o;
}

// ---------------- K1: kv GEMM (A reg-staged f32) + LN + P -------------------
// 1D grid 2048 (XCD-swizzled): wgid=(bid&7)*256+(bid>>3); rt=wgid>>3, h=wgid&7
__launch_bounds__(256, 3)
__global__ void k1_kvp(const float* __restrict__ x,
                       const unsigned short* __restrict__ wqkvb,
                       const float* __restrict__ gK, const float* __restrict__ bK,
                       const float* __restrict__ gV, const float* __restrict__ bV,
                       unsigned short* __restrict__ Ppart) {
  __shared__ __align__(16) unsigned short As[8192];   // 16 KB: A [128][64]
  __shared__ __align__(16) unsigned short Bs[8192];   // 16 KB: B [128][64]
  const int bid = (int)blockIdx.x;
  const int wgid = (bid & 7) * 256 + (bid >> 3);      // bijective (2048%8==0)
  const int rt = wgid >> 3, h = wgid & 7;
  const int tid = (int)threadIdx.x;
  const int l = tid & 63, w = tid >> 6;
  const int wr = w >> 1, wc = w & 1;
  const int g = l >> 4, c16 = l & 15;
  const int row0 = rt * 128;
  const int swz = ((l & 7) ^ (l >> 3)) * 8;           // logical col in 64-blk

  const float* gx = x + (size_t)(row0 + w * 32 + (l >> 3)) * 512 + swz;
  const int bcol = (w < 2) ? (512 + h * 64 + w * 32) : (1024 + h * 64 + (w - 2) * 32);
  const unsigned short* gsB = wqkvb + (bcol + (l >> 3)) * 512 + swz;
  unsigned short* la = As + w * 2048 + l * 8;         // + j*512 per row-slice

  f32x4 acc[4][4] = {};
  float4 pf[8];

  // prologue: A(0) f32 loads
#pragma unroll
  for (int j = 0; j < 4; ++j) {
    pf[2 * j]     = *(const float4*)(gx + j * 4096);
    pf[2 * j + 1] = *(const float4*)(gx + j * 4096 + 4);
  }

  for (int kt = 0; kt < 8; ++kt) {
    // convert + write A(kt) (compiler waits the pf loads here)
#pragma unroll
    for (int j = 0; j < 4; ++j) {
      u32x4 c;
      c[0] = cvt2(pf[2 * j].x, pf[2 * j].y);
      c[1] = cvt2(pf[2 * j].z, pf[2 * j].w);
      c[2] = cvt2(pf[2 * j + 1].x, pf[2 * j + 1].y);
      c[3] = cvt2(pf[2 * j + 1].z, pf[2 * j + 1].w);
      *(u32x4*)(la + j * 512) = c;
    }
    // stage B(kt) via global_load_lds
#pragma unroll
    for (int j = 0; j < 4; ++j)
      gload16(gsB + kt * 64 + j * 8 * 512, Bs + w * 2048 + j * 512);
    __builtin_amdgcn_sched_barrier(0);   // pin: B gloads BEFORE A prefetch
    if (kt < 7) {
      // prefetch A(kt+1) f32 -- stays in flight across the barrier
#pragma unroll
      for (int j = 0; j < 4; ++j) {
        pf[2 * j]     = *(const float4*)(gx + (kt + 1) * 64 + j * 4096);
        pf[2 * j + 1] = *(const float4*)(gx + (kt + 1) * 64 + j * 4096 + 4);
      }
      asm volatile("s_waitcnt vmcnt(8) lgkmcnt(0)" ::: "memory");
    } else {
      asm volatile("s_waitcnt vmcnt(0) lgkmcnt(0)" ::: "memory");
    }
    __builtin_amdgcn_sched_barrier(0);
    __builtin_amdgcn_s_barrier();        // tile ready
    // compute
#pragma unroll
    for (int ks = 0; ks < 2; ++ks) {
      const int kcol = (ks * 32 + g * 8) ^ ((c16 & 7) << 3);
      bf16x8 af[4], bfv[4];
#pragma unroll
      for (int mi = 0; mi < 4; ++mi)
        af[mi] = *(const bf16x8*)&As[(wr * 64 + mi * 16 + c16) * 64 + kcol];
#pragma unroll
      for (int ni = 0; ni < 4; ++ni)
        bfv[ni] = *(const bf16x8*)&Bs[(wc * 64 + ni * 16 + c16) * 64 + kcol];
#pragma unroll
      for (int mi = 0; mi < 4; ++mi)
#pragma unroll
        for (int ni = 0; ni < 4; ++ni)
          acc[mi][ni] = mfma16(af[mi], bfv[ni], acc[mi][ni]);
    }
    __builtin_amdgcn_sched_barrier(0);
    __builtin_amdgcn_s_barrier();        // LDS free for next kt's writes
  }

  // ---- per-head LayerNorm (wc=0 -> k, wc=1 -> v)
  const float* gamma = (wc == 0) ? gK : gV;
  const float* beta  = (wc == 0) ? bK : bV;
  float gm[4], bt[4];
#pragma unroll
  for (int ni = 0; ni < 4; ++ni) {
    gm[ni] = gamma[h * 64 + ni * 16 + c16];
    bt[ni] = beta[h * 64 + ni * 16 + c16];
  }
  // kn -> As ([64 d][128 n]), vn -> Bs
  unsigned short* dst = (wc == 0) ? As : Bs;
#pragma unroll
  for (int mi = 0; mi < 4; ++mi) {
    float mean4[4], rs4[4];
#pragma unroll
    for (int r = 0; r < 4; ++r) {
      float a0 = acc[mi][0][r], a1 = acc[mi][1][r];
      float a2 = acc[mi][2][r], a3 = acc[mi][3][r];
      float s1 = a0 + a1 + a2 + a3;
      float s2 = a0 * a0 + a1 * a1 + a2 * a2 + a3 * a3;
#pragma unroll
      for (int m = 1; m <= 8; m <<= 1) {   // reduce over 16-lane col group
        s1 += __shfl_xor(s1, m, 64);
        s2 += __shfl_xor(s2, m, 64);
      }
      const float mean = s1 * (1.0f / 64.0f);
      const float var = s2 * (1.0f / 64.0f) - mean * mean;
      mean4[r] = mean;
      rs4[r] = rsqrtf(var + 1e-5f);
    }
    const int n0 = wr * 64 + mi * 16 + g * 4;
#pragma unroll
    for (int ni = 0; ni < 4; ++ni) {
      u16x4 o;
#pragma unroll
      for (int r = 0; r < 4; ++r)
        o[r] = f2bf((acc[mi][ni][r] - mean4[r]) * rs4[r] * gm[ni] + bt[ni]);
      // phys8 = (n>>3) ^ (d&15); d&15 == c16
      *(u16x4*)&dst[(ni * 16 + c16) * 128 + (((n0 >> 3) ^ c16) << 3) + (n0 & 7)] = o;
    }
  }
  __syncthreads();

  // ---- P-partial: wave w covers dh rows w*16..w*16+15, all 64 dv, n=128
  f32x4 pacc[4] = {};
#pragma unroll
  for (int ks = 0; ks < 4; ++ks) {
    const int grp = ((ks * 4 + g) ^ c16) << 3;
    bf16x8 af = *(const bf16x8*)&As[(w * 16 + c16) * 128 + grp];
#pragma unroll
    for (int ni = 0; ni < 4; ++ni) {
      bf16x8 bv = *(const bf16x8*)&Bs[(ni * 16 + c16) * 128 + grp];
      pacc[ni] = mfma16(af, bv, pacc[ni]);
    }
  }
  // bf16 partial stores: Ppart[bh][slab][dh][dv], slab = rt & 63
  const int bh = (rt >> 6) * 8 + h;
  unsigned short* Pp = Ppart + ((size_t)(bh * 64 + (rt & 63))) * 4096;
#pragma unroll
  for (int ni = 0; ni < 4; ++ni)
#pragma unroll
    for (int r = 0; r < 4; ++r)
      Pp[(w * 16 + g * 4 + r) * 64 + ni * 16 + c16] = f2bf(pacc[ni][r]);
}

// ---------------- KR: P[bh] = sum over 64 slabs of Ppart (bf16) -------------
// grid (32, 16), 256 threads: each thread sums one P element over 64 slabs
__launch_bounds__(256)
__global__ void k_preduce(const unsigned short* __restrict__ Ppart,
                          float* __restrict__ P) {
  const int bh = blockIdx.x;
  const int e = blockIdx.y * 256 + threadIdx.x;
  const unsigned short* src = Ppart + (size_t)bh * 64 * 4096 + e;
  float s = 0.f;
#pragma unroll 8
  for (int sl = 0; sl < 64; ++sl) s += bf2f(src[sl * 4096]);
  P[bh * 4096 + e] = s;
}

// ------------- K3a: Gt[b][d][h*64+dv] = sum_dh P[bh][dh][dv]*Wq[h*64+dh][d]/n
__launch_bounds__(256)
__global__ void k3a_g(const float* __restrict__ Wqkv,
                      const float* __restrict__ P,
                      unsigned short* __restrict__ Gt) {
  __shared__ float Pl[64 * 64];
  const int bh = blockIdx.x, dd = blockIdx.y;
  const int b = bh >> 3, h = bh & 7;
  const int t = (int)threadIdx.x;
  for (int i = t; i < 1024; i += 256)
    ((float4*)Pl)[i] = ((const float4*)(P + bh * 4096))[i];
  __syncthreads();

  const int qg = t >> 6, dl = t & 63;
  const int d = dd * 64 + dl;
  float acc[16] = {};
  for (int dh = 0; dh < 64; ++dh) {
    const float wq = Wqkv[(h * 64 + dh) * 512 + d];
    const float* pr = &Pl[dh * 64 + qg * 16];
#pragma unroll
    for (int i = 0; i < 16; ++i) acc[i] += pr[i] * wq;
  }
  unsigned short* go = &Gt[(b * 512 + d) * 512 + h * 64 + qg * 16];
#pragma unroll
  for (int i = 0; i < 16; ++i) go[i] = f2bf(acc[i] * (1.0f / 8192.0f));
}

// ----------------------- 128^2 single-buffer GEMM pieces --------------------
__device__ __forceinline__ void stage_tile(const unsigned short* pa,
                                           const unsigned short* pb,
                                           unsigned short* As, unsigned short* Bs,
                                           int w) {
#pragma unroll
  for (int j = 0; j < 4; ++j) {
    gload16(pa + j * 8 * 512, As + w * 2048 + j * 512);
    gload16(pb + j * 8 * 512, Bs + w * 2048 + j * 512);
  }
}

__device__ __forceinline__ void compute_tile(const unsigned short* As,
                                             const unsigned short* Bs,
                                             int wr, int wc, int g, int c16,
                                             f32x4 acc[4][4]) {
#pragma unroll
  for (int ks = 0; ks < 2; ++ks) {
    const int kcol = (ks * 32 + g * 8) ^ ((c16 & 7) << 3);
    bf16x8 af[4], bfv[4];
#pragma unroll
    for (int mi = 0; mi < 4; ++mi)
      af[mi] = *(const bf16x8*)&As[(wr * 64 + mi * 16 + c16) * 64 + kcol];
#pragma unroll
    for (int ni = 0; ni < 4; ++ni)
      bfv[ni] = *(const bf16x8*)&Bs[(wc * 64 + ni * 16 + c16) * 64 + kcol];
#pragma unroll
    for (int mi = 0; mi < 4; ++mi)
#pragma unroll
      for (int ni = 0; ni < 4; ++ni)
        acc[mi][ni] = mfma16(af[mi], bfv[ni], acc[mi][ni]);
  }
}

// ----------- K3b: M_b[d'][d] = sum_e Wout[d'][e] * Gt_b[d][e] ---------------
__launch_bounds__(256)
__global__ void k3b_m(const unsigned short* __restrict__ wob,
                      const unsigned short* __restrict__ Gt,
                      unsigned short* __restrict__ Mb) {
  __shared__ __align__(16) unsigned short As[8192];
  __shared__ __align__(16) unsigned short Bs[8192];
  const int rt = blockIdx.x, ct = blockIdx.y, b = blockIdx.z;
  const int tid = (int)threadIdx.x;
  const int l = tid & 63, w = tid >> 6;
  const int wr = w >> 1, wc = w & 1;
  const int g = l >> 4, c16 = l & 15;
  const int row0 = rt * 128, col0 = ct * 128;
  const int swz = ((l & 7) ^ (l >> 3)) * 8;

  const unsigned short* gsA = wob + (row0 + w * 32 + (l >> 3)) * 512 + swz;
  const unsigned short* gsB = Gt + b * 262144 + (col0 + w * 32 + (l >> 3)) * 512 + swz;

  f32x4 acc[4][4] = {};
  for (int kt = 0; kt < 8; ++kt) {
    stage_tile(gsA + kt * 64, gsB + kt * 64, As, Bs, w);
    __syncthreads();
    compute_tile(As, Bs, wr, wc, g, c16, acc);
    __syncthreads();
  }

#pragma unroll
  for (int mi = 0; mi < 4; ++mi)
#pragma unroll
    for (int ni = 0; ni < 4; ++ni) {
      const int colg = col0 + wc * 64 + ni * 16 + c16;
#pragma unroll
      for (int r = 0; r < 4; ++r) {
        const int rowg = row0 + wr * 64 + mi * 16 + g * 4 + r;
        Mb[(b * 512 + rowg) * 512 + colg] = f2bf(acc[mi][ni][r]);
      }
    }
}

// ---------------- K4: y = x @ M_b^T + b_out (A reg-staged f32) --------------
// 1D grid 1024 (XCD-swizzled): wgid=(bid&7)*128+(bid>>3); rt=wgid>>2, ct=wgid&3
__launch_bounds__(256, 3)
__global__ void k4_final(const float* __restrict__ x,
                         const unsigned short* __restrict__ Mb,
                         const float* __restrict__ bout,
                         float* __restrict__ y) {
  __shared__ __align__(16) unsigned short As[8192];
  __shared__ __align__(16) unsigned short Bs[8192];
  const int bid = (int)blockIdx.x;
  const int wgid = (bid & 7) * 128 + (bid >> 3);      // bijective (1024%8==0)
  const int rt = wgid >> 2, ct = wgid & 3;
  const int tid = (int)threadIdx.x;
  const int l = tid & 63, w = tid >> 6;
  const int wr = w >> 1, wc = w & 1;
  const int g = l >> 4, c16 = l & 15;
  const int row0 = rt * 128, col0 = ct * 128;
  const int bb = row0 >> 13;
  const int swz = ((l & 7) ^ (l >> 3)) * 8;

  const float* gx = x + (size_t)(row0 + w * 32 + (l >> 3)) * 512 + swz;
  const unsigned short* gsB =
      Mb + (size_t)bb * 262144 + (col0 + w * 32 + (l >> 3)) * 512 + swz;
  unsigned short* la = As + w * 2048 + l * 8;

  f32x4 acc[4][4] = {};
  float4 pf[8];
#pragma unroll
  for (int j = 0; j < 4; ++j) {
    pf[2 * j]     = *(const float4*)(gx + j * 4096);
    pf[2 * j + 1] = *(const float4*)(gx + j * 4096 + 4);
  }

  for (int kt = 0; kt < 8; ++kt) {
#pragma unroll
    for (int j = 0; j < 4; ++j) {
      u32x4 c;
      c[0] = cvt2(pf[2 * j].x, pf[2 * j].y);
      c[1] = cvt2(pf[2 * j].z, pf[2 * j].w);
      c[2] = cvt2(pf[2 * j + 1].x, pf[2 * j + 1].y);
      c[3] = cvt2(pf[2 * j + 1].z, pf[2 * j + 1].w);
      *(u32x4*)(la + j * 512) = c;
    }
#pragma unroll
    for (int j = 0; j < 4; ++j)
      gload16(gsB + kt * 64 + j * 8 * 512, Bs + w * 2048 + j * 512);
    __builtin_amdgcn_sched_barrier(0);
    if (kt < 7) {
#pragma unroll
      for (int j = 0; j < 4; ++j) {
        pf[2 * j]     = *(const float4*)(gx + (kt + 1) * 64 + j * 4096);
        pf[2 * j + 1] = *(const float4*)(gx + (kt + 1) * 64 + j * 4096 + 4);
      }
      asm volatile("s_waitcnt vmcnt(8) lgkmcnt(0)" ::: "memory");
    } else {
      asm volatile("s_waitcnt vmcnt(0) lgkmcnt(0)" ::: "memory");
    }
    __builtin_amdgcn_sched_barrier(0);
    __builtin_amdgcn_s_barrier();
#pragma unroll
    for (int ks = 0; ks < 2; ++ks) {
      const int kcol = (ks * 32 + g * 8) ^ ((c16 & 7) << 3);
      bf16x8 af[4], bfv[4];
#pragma unroll
      for (int mi = 0; mi < 4; ++mi)
        af[mi] = *(const bf16x8*)&As[(wr * 64 + mi * 16 + c16) * 64 + kcol];
#pragma unroll
      for (int ni = 0; ni < 4; ++ni)
        bfv[ni] = *(const bf16x8*)&Bs[(wc * 64 + ni * 16 + c16) * 64 + kcol];
#pragma unroll
      for (int mi = 0; mi < 4; ++mi)
#pragma unroll
        for (int ni = 0; ni < 4; ++ni)
          acc[mi][ni] = mfma16(af[mi], bfv[ni], acc[mi][ni]);
    }
    __builtin_amdgcn_sched_barrier(0);
    __builtin_amdgcn_s_barrier();
  }

  float bo[4];
#pragma unroll
  for (int ni = 0; ni < 4; ++ni)
    bo[ni] = bout[col0 + wc * 64 + ni * 16 + c16];
#pragma unroll
  for (int mi = 0; mi < 4; ++mi)
#pragma unroll
    for (int ni = 0; ni < 4; ++ni) {
      const int colg = col0 + wc * 64 + ni * 16 + c16;
#pragma unroll
      for (int r = 0; r < 4; ++r) {
        const int rowg = row0 + wr * 64 + mi * 16 + g * 4 + r;
        y[rowg * 512 + colg] = acc[mi][ni][r] + bo[ni];
      }
    }
}

// ---------------------------------------------------------------------------
extern "C" void kernel_launch(void* const* d_in, const int* in_sizes, int n_in,
                              void* d_out, int out_size, void* d_ws, size_t ws_size,
                              hipStream_t stream) {
  (void)in_sizes; (void)n_in; (void)out_size; (void)ws_size;
  const float* x    = (const float*)d_in[0];
  const float* Wqkv = (const float*)d_in[1];
  const float* gK   = (const float*)d_in[2];
  const float* bK   = (const float*)d_in[3];
  const float* gV   = (const float*)d_in[4];
  const float* bV   = (const float*)d_in[5];
  const float* Wout = (const float*)d_in[6];
  const float* bout = (const float*)d_in[7];
  float* y = (float*)d_out;

  // workspace carve (~23 MB)
  char* w = (char*)d_ws;
  unsigned short* Wb    = (unsigned short*)(w);             //  1,572,864
  unsigned short* Wob   = (unsigned short*)(w + 1572864);   //    524,288
  float*          P     = (float*)         (w + 2097152);   //    524,288
  unsigned short* Gt    = (unsigned short*)(w + 2621440);   //  2,097,152
  unsigned short* Mb    = (unsigned short*)(w + 4718592);   //  2,097,152
  unsigned short* Ppart = (unsigned short*)(w + 6815744);   // 16,777,216

  k_cvt_w<<<1024, 256, 0, stream>>>(Wqkv, Wout, Wb, Wob);

  k1_kvp<<<2048, 256, 0, stream>>>(x, Wb, gK, bK, gV, bV, Ppart);
  k_preduce<<<dim3(32, 16), 256, 0, stream>>>(Ppart, P);
  k3a_g<<<dim3(32, 8), 256, 0, stream>>>(Wqkv, P, Gt);
  k3b_m<<<dim3(4, 4, 4), 256, 0, stream>>>(Wob, Gt, Mb);
  k4_final<<<1024, 256, 0, stream>>>(x, Mb, bout, y);
}